// Round 1
// baseline (370.312 us; speedup 1.0000x reference)
//
#include <hip/hip_runtime.h>

#define B_   4
#define C_   512
#define S_   4096
#define G_   32
#define CPG_ 16
#define EPS_ 1e-6f

typedef unsigned short u16;
typedef __bf16 bf16x8 __attribute__((ext_vector_type(8)));
typedef float  f32x4  __attribute__((ext_vector_type(4)));

__device__ __forceinline__ u16 f2bf(float f) {
  unsigned u = __float_as_uint(f);
  u += 0x7fffu + ((u >> 16) & 1u);   // RNE
  return (u16)(u >> 16);
}
__device__ __forceinline__ float bf2f(u16 h) {
  return __uint_as_float((unsigned)h << 16);
}

__device__ __forceinline__ void g2lds16(const void* g, void* l) {
  __builtin_amdgcn_global_load_lds(
      (const __attribute__((address_space(1))) void*)g,
      (__attribute__((address_space(3))) void*)l, 16, 0, 0);
}

// ---------------- fp32 -> bf16 weight conversion ----------------
__global__ __launch_bounds__(256) void f32_to_bf16(const float* __restrict__ in,
                                                   u16* __restrict__ out, int n) {
  int i = blockIdx.x * 256 + threadIdx.x;
  if (i < n) out[i] = f2bf(in[i]);
}

// ---------------- GroupNorm stats: one block per (b,g) ----------------
__global__ __launch_bounds__(256) void gn_stats(const float* __restrict__ x,
                                                float* __restrict__ stats) {
  const int bg = blockIdx.x;  // b*32+g ; group data is contiguous 16*S floats
  const float4* p4 = (const float4*)(x + (size_t)bg * (CPG_ * S_));
  float s = 0.f, ss = 0.f;
  const int tid = threadIdx.x;
  for (int i = tid; i < CPG_ * S_ / 4; i += 256) {
    float4 v = p4[i];
    s  += v.x + v.y + v.z + v.w;
    ss += v.x * v.x + v.y * v.y + v.z * v.z + v.w * v.w;
  }
#pragma unroll
  for (int o = 32; o; o >>= 1) { s += __shfl_xor(s, o, 64); ss += __shfl_xor(ss, o, 64); }
  __shared__ float sm[8];
  const int wid = tid >> 6, lane = tid & 63;
  if (lane == 0) { sm[wid * 2] = s; sm[wid * 2 + 1] = ss; }
  __syncthreads();
  if (tid == 0) {
    s  = sm[0] + sm[2] + sm[4] + sm[6];
    ss = sm[1] + sm[3] + sm[5] + sm[7];
    const float inv = 1.f / (float)(CPG_ * S_);
    float mu = s * inv;
    float var = ss * inv - mu * mu;
    stats[bg * 2]     = mu;
    stats[bg * 2 + 1] = rsqrtf(var + EPS_);
  }
}

// ---------------- normalize + transpose: x[b,c,s] -> ht[b*s, c] bf16 ----------------
__global__ __launch_bounds__(256) void gn_apply_t(const float* __restrict__ x,
                                                  const float* __restrict__ gamma,
                                                  const float* __restrict__ beta,
                                                  const float* __restrict__ stats,
                                                  u16* __restrict__ ht) {
  __shared__ float tile[32][33];
  const int b = blockIdx.z, c0 = blockIdx.y * 32, s0 = blockIdx.x * 32;
  const int tx = threadIdx.x, ty = threadIdx.y;
#pragma unroll
  for (int i = 0; i < 4; ++i) {
    const int c  = c0 + ty + i * 8;
    const float mu = stats[(b * G_ + (c >> 4)) * 2];
    const float rs = stats[(b * G_ + (c >> 4)) * 2 + 1];
    const float v  = x[((size_t)b * C_ + c) * S_ + s0 + tx];
    tile[ty + i * 8][tx] = (v - mu) * rs * gamma[c] + beta[c];
  }
  __syncthreads();
#pragma unroll
  for (int i = 0; i < 4; ++i) {
    const int s = s0 + ty + i * 8;
    ht[((size_t)b * S_ + s) * C_ + c0 + tx] = f2bf(tile[tx][ty + i * 8]);
  }
}

// ---------------- GEMM: C[m,n] = alpha * sum_k A[m,k]*B[n,k] (+bias) ----------------
// A,B bf16 row-major (K contiguous). m97 structure: 128x128 tile, BK=64,
// 4 waves (2x2), global_load_lds width 16, linear LDS, 2 barriers/K-step.
// BIAS_MODE: 0 none, 1 bias[n], 2 bias[m].
// OUT_MODE:  0 bf16 C[m*ldc+n]; 1 fp32 out[b,o,s] = acc + bias[m] + x[b,o,s] with n = b*S+s.
#define GBM 128
#define GBN 128
#define GBK 64

template <int BIAS_MODE, int OUT_MODE>
__global__ __launch_bounds__(256) void gemm_abT(
    const u16* __restrict__ Ag, int lda, long sA,
    const u16* __restrict__ Bg, int ldb, long sB,
    void* __restrict__ Cg, int ldc, long sC,
    const float* __restrict__ bias, float alpha,
    const float* __restrict__ xres, int K) {
  __shared__ u16 As[GBM * GBK];
  __shared__ u16 Bs[GBN * GBK];
  const int bz = blockIdx.z;
  const u16* A    = Ag + (size_t)bz * sA;
  const u16* Bmat = Bg + (size_t)bz * sB;
  const int bm = blockIdx.y * GBM, bn = blockIdx.x * GBN;
  const int tid = threadIdx.x;
  const int wid = tid >> 6, lane = tid & 63;
  const int wm = (wid >> 1) * 64, wn = (wid & 1) * 64;
  const int lr = lane & 15, lh = lane >> 4;
  const int srow = lane >> 3, scol = (lane & 7) * 8;

  f32x4 acc[4][4];
  const f32x4 zero = {0.f, 0.f, 0.f, 0.f};
#pragma unroll
  for (int i = 0; i < 4; ++i)
#pragma unroll
    for (int j = 0; j < 4; ++j) acc[i][j] = zero;

  for (int k0 = 0; k0 < K; k0 += GBK) {
    __syncthreads();  // protect LDS from previous iteration's readers
#pragma unroll
    for (int i = 0; i < 4; ++i) {
      const int chunk = wid * 4 + i;         // 0..15 -> rows 8*chunk..8*chunk+7
      const int row   = chunk * 8 + srow;
      g2lds16(A    + (size_t)(bm + row) * lda + (k0 + scol), &As[chunk * 512]);
      g2lds16(Bmat + (size_t)(bn + row) * ldb + (k0 + scol), &Bs[chunk * 512]);
    }
    __syncthreads();  // vmcnt(0) drained by compiler before barrier
#pragma unroll
    for (int ks = 0; ks < 2; ++ks) {
      bf16x8 a_[4], b_[4];
#pragma unroll
      for (int m = 0; m < 4; ++m)
        a_[m] = *(const bf16x8*)&As[(wm + m * 16 + lr) * GBK + ks * 32 + lh * 8];
#pragma unroll
      for (int n = 0; n < 4; ++n)
        b_[n] = *(const bf16x8*)&Bs[(wn + n * 16 + lr) * GBK + ks * 32 + lh * 8];
#pragma unroll
      for (int m = 0; m < 4; ++m)
#pragma unroll
        for (int n = 0; n < 4; ++n)
          acc[m][n] = __builtin_amdgcn_mfma_f32_16x16x32_bf16(a_[m], b_[n], acc[m][n], 0, 0, 0);
    }
  }

  if (OUT_MODE == 0) {
    u16* Cb = (u16*)Cg + (size_t)bz * sC;
#pragma unroll
    for (int m = 0; m < 4; ++m) {
      const int row0 = bm + wm + m * 16 + lh * 4;
#pragma unroll
      for (int n = 0; n < 4; ++n) {
        const int col = bn + wn + n * 16 + lr;
        float bn_ = (BIAS_MODE == 1) ? bias[col] : 0.f;
#pragma unroll
        for (int r = 0; r < 4; ++r) {
          float bb = (BIAS_MODE == 2) ? bias[row0 + r] : bn_;
          Cb[(size_t)(row0 + r) * ldc + col] = f2bf(acc[m][n][r] * alpha + bb);
        }
      }
    }
  } else {
    float* Ob = (float*)Cg;  // full [B,C,S] output
#pragma unroll
    for (int m = 0; m < 4; ++m) {
      const int row0 = bm + wm + m * 16 + lh * 4;  // output channel o
#pragma unroll
      for (int n = 0; n < 4; ++n) {
        const int col = bn + wn + n * 16 + lr;     // b*S + s
        const int bb = col >> 12, sp = col & (S_ - 1);
#pragma unroll
        for (int r = 0; r < 4; ++r) {
          const int o = row0 + r;
          const size_t idx = ((size_t)bb * C_ + o) * S_ + sp;
          Ob[idx] = acc[m][n][r] * alpha + bias[o] + xres[idx];
        }
      }
    }
  }
}

// ---------------- row softmax, in place on bf16 scores ----------------
__global__ __launch_bounds__(256) void softmax_rows(u16* __restrict__ sc) {
  const size_t base = ((size_t)blockIdx.y * S_ + blockIdx.x) * S_;
  uint4* r4 = (uint4*)(sc + base);
  const int tid = threadIdx.x;
  uint4 u0 = r4[tid], u1 = r4[tid + 256];
  float f[16];
  {
    const unsigned* pu = (const unsigned*)&u0;
    const unsigned* pv = (const unsigned*)&u1;
#pragma unroll
    for (int i = 0; i < 4; ++i) {
      f[2 * i]     = bf2f((u16)(pu[i] & 0xffffu));
      f[2 * i + 1] = bf2f((u16)(pu[i] >> 16));
      f[8 + 2 * i]     = bf2f((u16)(pv[i] & 0xffffu));
      f[8 + 2 * i + 1] = bf2f((u16)(pv[i] >> 16));
    }
  }
  float mx = f[0];
#pragma unroll
  for (int i = 1; i < 16; ++i) mx = fmaxf(mx, f[i]);
#pragma unroll
  for (int o = 32; o; o >>= 1) mx = fmaxf(mx, __shfl_xor(mx, o, 64));
  __shared__ float red[8];
  const int wid = tid >> 6, lane = tid & 63;
  if (lane == 0) red[wid] = mx;
  __syncthreads();
  mx = fmaxf(fmaxf(red[0], red[1]), fmaxf(red[2], red[3]));
  float s = 0.f;
#pragma unroll
  for (int i = 0; i < 16; ++i) { f[i] = __expf(f[i] - mx); s += f[i]; }
#pragma unroll
  for (int o = 32; o; o >>= 1) s += __shfl_xor(s, o, 64);
  if (lane == 0) red[4 + wid] = s;
  __syncthreads();
  s = red[4] + red[5] + red[6] + red[7];
  const float inv = 1.f / s;
  unsigned o0[4], o1[4];
#pragma unroll
  for (int i = 0; i < 4; ++i) {
    o0[i] = (unsigned)f2bf(f[2 * i] * inv)     | ((unsigned)f2bf(f[2 * i + 1] * inv) << 16);
    o1[i] = (unsigned)f2bf(f[8 + 2 * i] * inv) | ((unsigned)f2bf(f[8 + 2 * i + 1] * inv) << 16);
  }
  r4[tid]       = *(uint4*)o0;
  r4[tid + 256] = *(uint4*)o1;
}

extern "C" void kernel_launch(void* const* d_in, const int* in_sizes, int n_in,
                              void* d_out, int out_size, void* d_ws, size_t ws_size,
                              hipStream_t stream) {
  const float* x     = (const float*)d_in[0];
  const float* gamma = (const float*)d_in[1];
  const float* beta  = (const float*)d_in[2];
  const float* wq = (const float*)d_in[3];
  const float* bq = (const float*)d_in[4];
  const float* wk = (const float*)d_in[5];
  const float* bk = (const float*)d_in[6];
  const float* wv = (const float*)d_in[7];
  const float* bv = (const float*)d_in[8];
  const float* wo = (const float*)d_in[9];
  const float* bo = (const float*)d_in[10];
  float* out = (float*)d_out;

  // workspace layout (bytes): stats 1KB | 4 bf16 weights | ht | qt | kt | v | scores
  char* ws = (char*)d_ws;
  float* stats = (float*)ws;
  u16* wqb = (u16*)(ws + 1024);
  u16* wkb = wqb + 262144;
  u16* wvb = wkb + 262144;
  u16* wob = wvb + 262144;
  u16* ht  = wob + 262144;        // [B*S, C]
  u16* qt  = ht + 8388608;        // [B*S, C]
  u16* kt  = qt + 8388608;        // [B*S, C]
  u16* vv  = kt + 8388608;        // [C, B*S]
  u16* sc  = vv + 8388608;        // [B, S, S]
  u16* ha  = qt;                  // hattnT reuses qt (dead after scores GEMM)

  f32_to_bf16<<<1024, 256, 0, stream>>>(wq, wqb, 262144);
  f32_to_bf16<<<1024, 256, 0, stream>>>(wk, wkb, 262144);
  f32_to_bf16<<<1024, 256, 0, stream>>>(wv, wvb, 262144);
  f32_to_bf16<<<1024, 256, 0, stream>>>(wo, wob, 262144);

  gn_stats<<<128, 256, 0, stream>>>(x, stats);
  gn_apply_t<<<dim3(128, 16, 4), dim3(32, 8), 0, stream>>>(x, gamma, beta, stats, ht);

  // Qt[bs,o] / Kt[bs,o]
  gemm_abT<1, 0><<<dim3(4, 128, 1), 256, 0, stream>>>(ht, 512, 0, wqb, 512, 0,
                                                      qt, 512, 0, bq, 1.f, nullptr, 512);
  gemm_abT<1, 0><<<dim3(4, 128, 1), 256, 0, stream>>>(ht, 512, 0, wkb, 512, 0,
                                                      kt, 512, 0, bk, 1.f, nullptr, 512);
  // V[c, b*S+s]
  gemm_abT<2, 0><<<dim3(128, 4, 1), 256, 0, stream>>>(wvb, 512, 0, ht, 512, 0,
                                                      vv, 16384, 0, bv, 1.f, nullptr, 512);
  // scores[b,i,j] = scale * Qt_b[i,:].Kt_b[j,:]
  gemm_abT<0, 0><<<dim3(32, 32, 4), 256, 0, stream>>>(qt, 512, 2097152, kt, 512, 2097152,
                                                      sc, 4096, 16777216, nullptr,
                                                      0.04419417382415922f, nullptr, 512);
  softmax_rows<<<dim3(4096, 4), 256, 0, stream>>>(sc);
  // hattnT[b*S+i, c] = sum_j P_b[i,j] * V_b[c,j]
  gemm_abT<0, 0><<<dim3(4, 32, 4), 256, 0, stream>>>(sc, 4096, 16777216, vv, 16384, 4096,
                                                     ha, 512, 2097152, nullptr, 1.f, nullptr, 4096);
  // out[b,o,s] = Wo@hattn + bo + x
  gemm_abT<2, 1><<<dim3(128, 4, 1), 256, 0, stream>>>(wob, 512, 0, ha, 512, 0,
                                                      out, 0, 0, bo, 1.f, x, 512);
}